// Round 3
// baseline (443.510 us; speedup 1.0000x reference)
//
#include <hip/hip_runtime.h>
#include <hip/hip_bf16.h>
#include <cfloat>
#include <math.h>

// ---------------- types ----------------
typedef __bf16 bf16x8 __attribute__((ext_vector_type(8)));
typedef float  f32x4  __attribute__((ext_vector_type(4)));

#define AMSM_MARGIN 0.35f
#define AMSM_SCALE  30.0f
#define AMSM_EPS    1e-12f

// ---------------- kernel 1/2: row-normalize f32 -> bf16 ----------------
// one wave per row, 4 rows per 256-thread block. rows >= nrows (pad) -> zeros.
__global__ __launch_bounds__(256) void rownorm_bf16(
    const float* __restrict__ src, __bf16* __restrict__ dst,
    int nrows, int nrows_pad)
{
    int row  = blockIdx.x * 4 + (threadIdx.x >> 6);
    int lane = threadIdx.x & 63;
    if (row >= nrows_pad) return;

    __bf16* drow = dst + (size_t)row * 512 + lane * 8;

    if (row >= nrows) {           // zero-fill pad rows (keeps MFMA garbage-free)
        bf16x8 z = {};
        *(bf16x8*)drow = z;
        return;
    }
    const float4* p = (const float4*)(src + (size_t)row * 512 + lane * 8);
    float4 a = p[0], b = p[1];
    float ss = a.x*a.x + a.y*a.y + a.z*a.z + a.w*a.w
             + b.x*b.x + b.y*b.y + b.z*b.z + b.w*b.w;
    #pragma unroll
    for (int m = 1; m < 64; m <<= 1) ss += __shfl_xor(ss, m, 64);
    float r = 1.0f / sqrtf(ss + AMSM_EPS);

    bf16x8 o;
    o[0] = (__bf16)(a.x*r); o[1] = (__bf16)(a.y*r);
    o[2] = (__bf16)(a.z*r); o[3] = (__bf16)(a.w*r);
    o[4] = (__bf16)(b.x*r); o[5] = (__bf16)(b.y*r);
    o[6] = (__bf16)(b.z*r); o[7] = (__bf16)(b.w*r);
    *(bf16x8*)drow = o;
}

// ---------------- kernel 3: fused GEMM + partial logsumexp ----------------
// tile: BM=128 rows(x) x BN=128 cols(classes), 4 waves (2x2 of 64x64),
// K-loop BK=32, 16x16x32 bf16 MFMA, global_load_lds(16B) staging.
// epilogue: margin at target, per-row (max, sum(exp)) over each wave's
// 64-col stripe -> pmax/psum[n][ctile*2+wc]; exact target logit -> tgt[n].
#define GBM 128
#define GBN 128
#define GBK 32
#define GD  512

__device__ __forceinline__ void load_lds16(const void* g, void* l) {
    __builtin_amdgcn_global_load_lds(
        (const __attribute__((address_space(1))) void*)g,
        (__attribute__((address_space(3))) void*)l, 16, 0, 0);
}

__global__ __launch_bounds__(256) void amsm_gemm(
    const __bf16* __restrict__ xn, const __bf16* __restrict__ Wn,
    const int* __restrict__ lb,
    float* __restrict__ pmax, float* __restrict__ psum,
    float* __restrict__ tgt, int C, int CHUNKS)
{
    __shared__ __bf16 Alds[GBM * GBK];   // [128][32]
    __shared__ __bf16 Blds[GBN * GBK];   // [128][32]

    const int m0 = blockIdx.x * GBM;     // grid.x = 16 (fast dim -> L2 reuse of W chunk)
    const int ctile = blockIdx.y;
    const int c0 = ctile * GBN;
    const int tid  = threadIdx.x;
    const int lane = tid & 63;
    const int w    = tid >> 6;
    const int wr   = w >> 1, wc = w & 1;
    const int g    = lane >> 4;          // k-subgroup 0..3
    const int lo   = lane & 15;

    f32x4 acc[4][4] = {};

    for (int k0 = 0; k0 < GD; k0 += GBK) {
        __syncthreads();   // previous iter's LDS reads done
        // stage A: 8KB = 2 issues of 256 threads x 16B
        #pragma unroll
        for (int iss = 0; iss < 2; ++iss) {
            int q = iss * 256 + tid;                       // 16B-chunk index
            const __bf16* gp = xn + (size_t)(m0 + (q >> 2)) * GD + k0 + (q & 3) * 8;
            load_lds16(gp, Alds + (iss * 256 + w * 64) * 8);
        }
        // stage B
        #pragma unroll
        for (int iss = 0; iss < 2; ++iss) {
            int q = iss * 256 + tid;
            const __bf16* gp = Wn + (size_t)(c0 + (q >> 2)) * GD + k0 + (q & 3) * 8;
            load_lds16(gp, Blds + (iss * 256 + w * 64) * 8);
        }
        __syncthreads();   // staging (vmcnt) drained by barrier semantics

        bf16x8 af[4], bf[4];
        #pragma unroll
        for (int mi = 0; mi < 4; ++mi)
            af[mi] = *(const bf16x8*)(Alds + (wr * 64 + mi * 16 + lo) * GBK + g * 8);
        #pragma unroll
        for (int ni = 0; ni < 4; ++ni)
            bf[ni] = *(const bf16x8*)(Blds + (wc * 64 + ni * 16 + lo) * GBK + g * 8);
        #pragma unroll
        for (int mi = 0; mi < 4; ++mi)
            #pragma unroll
            for (int ni = 0; ni < 4; ++ni)
                acc[mi][ni] = __builtin_amdgcn_mfma_f32_16x16x32_bf16(
                    af[mi], bf[ni], acc[mi][ni], 0, 0, 0);
    }

    // ---- epilogue: C/D map col=lane&15, row=(lane>>4)*4+reg ----
    const int n_base = m0 + wr * 64;
    const int c_base = c0 + wc * 64;
    const int chunk  = ctile * 2 + wc;

    #pragma unroll
    for (int mi = 0; mi < 4; ++mi) {
        #pragma unroll
        for (int j = 0; j < 4; ++j) {
            const int n = n_base + mi * 16 + g * 4 + j;
            const int target = lb[n];
            float vals[4];
            float vmax = -FLT_MAX;
            #pragma unroll
            for (int ni = 0; ni < 4; ++ni) {
                const int c = c_base + ni * 16 + lo;
                float logit;
                if (c < C) {
                    float cosv = acc[mi][ni][j];
                    if (c == target) {
                        logit = AMSM_SCALE * (cosv - AMSM_MARGIN);
                        tgt[n] = logit;                  // unique writer globally
                    } else {
                        logit = AMSM_SCALE * cosv;
                    }
                } else {
                    logit = -FLT_MAX;                    // masked tail column
                }
                vals[ni] = logit;
                vmax = fmaxf(vmax, logit);
            }
            // butterfly over the 16 lanes (low 4 lane bits) holding this row
            #pragma unroll
            for (int m = 1; m < 16; m <<= 1) vmax = fmaxf(vmax, __shfl_xor(vmax, m, 64));
            float s = 0.f;
            #pragma unroll
            for (int ni = 0; ni < 4; ++ni)
                s += (vals[ni] > -0.5f * FLT_MAX) ? __expf(vals[ni] - vmax) : 0.f;
            #pragma unroll
            for (int m = 1; m < 16; m <<= 1) s += __shfl_xor(s, m, 64);

            if (lo == 0) {
                pmax[(size_t)n * CHUNKS + chunk] = vmax;
                psum[(size_t)n * CHUNKS + chunk] = s;
            }
        }
    }
}

// ---------------- kernel 4: per-row combine of partials ----------------
__global__ __launch_bounds__(256) void row_reduce(
    const float* __restrict__ pmax, const float* __restrict__ psum,
    const float* __restrict__ tgt, float* __restrict__ row_loss, int CHUNKS)
{
    const int n = blockIdx.x;
    const int tid = threadIdx.x;
    __shared__ float sm[256];

    float m = -FLT_MAX;
    for (int j = tid; j < CHUNKS; j += 256) m = fmaxf(m, pmax[(size_t)n * CHUNKS + j]);
    sm[tid] = m; __syncthreads();
    for (int s = 128; s > 0; s >>= 1) {
        if (tid < s) sm[tid] = fmaxf(sm[tid], sm[tid + s]);
        __syncthreads();
    }
    const float M = sm[0];
    __syncthreads();

    float s = 0.f;
    for (int j = tid; j < CHUNKS; j += 256) {
        float pm = pmax[(size_t)n * CHUNKS + j];
        float ps = psum[(size_t)n * CHUNKS + j];
        s += (pm > -0.5f * FLT_MAX) ? ps * __expf(pm - M) : 0.f;
    }
    sm[tid] = s; __syncthreads();
    for (int st = 128; st > 0; st >>= 1) {
        if (tid < st) sm[tid] += sm[tid + st];
        __syncthreads();
    }
    if (tid == 0) row_loss[n] = (logf(sm[0]) + M) - tgt[n];
}

// ---------------- kernel 5: mean over rows -> scalar ----------------
__global__ __launch_bounds__(256) void final_reduce(
    const float* __restrict__ row_loss, float* __restrict__ out, int N)
{
    const int tid = threadIdx.x;
    __shared__ float sm[256];
    float s = 0.f;
    for (int i = tid; i < N; i += 256) s += row_loss[i];
    sm[tid] = s; __syncthreads();
    for (int st = 128; st > 0; st >>= 1) {
        if (tid < st) sm[tid] += sm[tid + st];
        __syncthreads();
    }
    if (tid == 0) out[0] = sm[0] / (float)N;
}

// ---------------- launch ----------------
extern "C" void kernel_launch(void* const* d_in, const int* in_sizes, int n_in,
                              void* d_out, int out_size, void* d_ws, size_t ws_size,
                              hipStream_t stream) {
    const float* x  = (const float*)d_in[0];
    const float* W  = (const float*)d_in[1];
    const int*   lb = (const int*)d_in[2];
    float* out = (float*)d_out;

    constexpr int N  = 2048, D = 512, C = 100000;
    constexpr int CT = (C + GBN - 1) / GBN;   // 782 column tiles
    constexpr int C_PAD = CT * GBN;           // 100096
    constexpr int CHUNKS = CT * 2;            // 1564 (one per 64-col wave stripe)

    char* ws = (char*)d_ws;
    auto alloc = [&](size_t bytes) {
        char* p = ws; ws += (bytes + 255) & ~(size_t)255; return p;
    };
    __bf16* Wn   = (__bf16*)alloc((size_t)C_PAD * D * sizeof(__bf16)); // 102.5 MB
    __bf16* xn   = (__bf16*)alloc((size_t)N * D * sizeof(__bf16));     // 2 MB
    float*  pmax = (float*)alloc((size_t)N * CHUNKS * sizeof(float));  // 12.8 MB
    float*  psum = (float*)alloc((size_t)N * CHUNKS * sizeof(float));  // 12.8 MB
    float*  tgtv = (float*)alloc((size_t)N * sizeof(float));
    float*  rl   = (float*)alloc((size_t)N * sizeof(float));

    rownorm_bf16<<<N / 4, 256, 0, stream>>>(x, xn, N, N);
    rownorm_bf16<<<C_PAD / 4, 256, 0, stream>>>(W, Wn, C, C_PAD);

    dim3 grid(N / GBM, CT);   // m-tiles fastest -> consecutive blocks share W chunk
    amsm_gemm<<<grid, 256, 0, stream>>>(xn, Wn, lb, pmax, psum, tgtv, C, CHUNKS);

    row_reduce<<<N, 256, 0, stream>>>(pmax, psum, tgtv, rl, CHUNKS);
    final_reduce<<<1, 256, 0, stream>>>(rl, out, N);
}

// Round 4
// 395.877 us; speedup vs baseline: 1.1203x; 1.1203x over previous
//
#include <hip/hip_runtime.h>
#include <hip/hip_bf16.h>
#include <cfloat>
#include <math.h>

// ---------------- types ----------------
typedef __bf16 bf16x8 __attribute__((ext_vector_type(8)));
typedef float  f32x4  __attribute__((ext_vector_type(4)));

#define AMSM_MARGIN 0.35f
#define AMSM_SCALE  30.0f
#define AMSM_EPS    1e-12f

// ---------------- kernel 1/2: row-normalize f32 -> bf16 ----------------
__global__ __launch_bounds__(256) void rownorm_bf16(
    const float* __restrict__ src, __bf16* __restrict__ dst,
    int nrows, int nrows_pad)
{
    int row  = blockIdx.x * 4 + (threadIdx.x >> 6);
    int lane = threadIdx.x & 63;
    if (row >= nrows_pad) return;

    __bf16* drow = dst + (size_t)row * 512 + lane * 8;

    if (row >= nrows) {           // zero-fill pad rows (keeps MFMA garbage-free)
        bf16x8 z = {};
        *(bf16x8*)drow = z;
        return;
    }
    const float4* p = (const float4*)(src + (size_t)row * 512 + lane * 8);
    float4 a = p[0], b = p[1];
    float ss = a.x*a.x + a.y*a.y + a.z*a.z + a.w*a.w
             + b.x*b.x + b.y*b.y + b.z*b.z + b.w*b.w;
    #pragma unroll
    for (int m = 1; m < 64; m <<= 1) ss += __shfl_xor(ss, m, 64);
    float r = 1.0f / sqrtf(ss + AMSM_EPS);

    bf16x8 o;
    o[0] = (__bf16)(a.x*r); o[1] = (__bf16)(a.y*r);
    o[2] = (__bf16)(a.z*r); o[3] = (__bf16)(a.w*r);
    o[4] = (__bf16)(b.x*r); o[5] = (__bf16)(b.y*r);
    o[6] = (__bf16)(b.z*r); o[7] = (__bf16)(b.w*r);
    *(bf16x8*)drow = o;
}

// ---------------- kernel 3: fused GEMM + partial sum-exp ----------------
// 2-phase double-buffered schedule (T3-minimum): STAGE(t+1) issued BEFORE
// ds_read+MFMA of tile t; ONE __syncthreads per K-step (its implicit
// vmcnt(0) lands ~1300 MFMA-cycles after the loads were issued).
// Epilogue uses the analytic max bound (logit <= SCALE): sum exp(logit-30)
// directly -- no per-row max tracking, no pmax buffer.
#define GBM 128
#define GBN 128
#define GBK 32
#define GD  512
#define NT  (GD / GBK)   // 16 K-steps

__device__ __forceinline__ void load_lds16(const void* g, void* l) {
    __builtin_amdgcn_global_load_lds(
        (const __attribute__((address_space(1))) void*)g,
        (__attribute__((address_space(3))) void*)l, 16, 0, 0);
}

__global__ __launch_bounds__(256) void amsm_gemm(
    const __bf16* __restrict__ xn, const __bf16* __restrict__ Wn,
    const int* __restrict__ lb,
    float* __restrict__ psum, float* __restrict__ tgt, int C, int CHUNKS)
{
    __shared__ __bf16 Alds[2][GBM * GBK];   // 2 x [128][32] bf16 = 2 x 8KB
    __shared__ __bf16 Blds[2][GBN * GBK];

    const int m0 = blockIdx.x * GBM;     // grid.x = 16 (fast dim -> W chunk L2 reuse)
    const int ctile = blockIdx.y;
    const int c0 = ctile * GBN;
    const int tid  = threadIdx.x;
    const int lane = tid & 63;
    const int w    = tid >> 6;
    const int wr   = w >> 1, wc = w & 1;
    const int g    = lane >> 4;          // k-subgroup 0..3
    const int lo   = lane & 15;

    // stage one 8KB A-tile + 8KB B-tile into buffer `buf` for K-offset k0
    auto stage = [&](int buf, int k0) {
        #pragma unroll
        for (int iss = 0; iss < 2; ++iss) {
            int q = iss * 256 + tid;                       // 16B-chunk index
            load_lds16(xn + (size_t)(m0 + (q >> 2)) * GD + k0 + (q & 3) * 8,
                       &Alds[buf][(iss * 256 + w * 64) * 8]);
        }
        #pragma unroll
        for (int iss = 0; iss < 2; ++iss) {
            int q = iss * 256 + tid;
            load_lds16(Wn + (size_t)(c0 + (q >> 2)) * GD + k0 + (q & 3) * 8,
                       &Blds[buf][(iss * 256 + w * 64) * 8]);
        }
    };

    f32x4 acc[4][4] = {};

    stage(0, 0);
    __syncthreads();                     // publish buf0 (vmcnt(0) implicit)

    #pragma unroll
    for (int t = 0; t < NT; ++t) {
        const int cur = t & 1;
        if (t + 1 < NT) stage(cur ^ 1, (t + 1) * GBK);   // prefetch next tile

        bf16x8 af[4], bfr[4];
        #pragma unroll
        for (int mi = 0; mi < 4; ++mi)
            af[mi] = *(const bf16x8*)(&Alds[cur][(wr * 64 + mi * 16 + lo) * GBK + g * 8]);
        #pragma unroll
        for (int ni = 0; ni < 4; ++ni)
            bfr[ni] = *(const bf16x8*)(&Blds[cur][(wc * 64 + ni * 16 + lo) * GBK + g * 8]);
        #pragma unroll
        for (int mi = 0; mi < 4; ++mi)
            #pragma unroll
            for (int ni = 0; ni < 4; ++ni)
                acc[mi][ni] = __builtin_amdgcn_mfma_f32_16x16x32_bf16(
                    af[mi], bfr[ni], acc[mi][ni], 0, 0, 0);

        __syncthreads();   // drains prefetch (vmcnt(0)) -> next buf published
    }

    // ---- epilogue: C/D map col=lane&15, row=(lane>>4)*4+reg ----
    const int n_base = m0 + wr * 64;
    const int c_base = c0 + wc * 64;
    const int chunk  = ctile * 2 + wc;

    #pragma unroll
    for (int mi = 0; mi < 4; ++mi) {
        #pragma unroll
        for (int j = 0; j < 4; ++j) {
            const int n = n_base + mi * 16 + g * 4 + j;
            const int target = lb[n];
            float s = 0.f;
            #pragma unroll
            for (int ni = 0; ni < 4; ++ni) {
                const int c = c_base + ni * 16 + lo;
                float logit = AMSM_SCALE * acc[mi][ni][j];
                if (c == target) {
                    logit -= AMSM_SCALE * AMSM_MARGIN;
                    tgt[n] = logit;                      // unique writer globally
                }
                // analytic max bound: logit <= SCALE; exp(logit-SCALE) in [2e-31, 1]
                s += (c < C) ? __expf(logit - AMSM_SCALE) : 0.f;
            }
            #pragma unroll
            for (int m = 1; m < 16; m <<= 1) s += __shfl_xor(s, m, 64);
            if (lo == 0) psum[(size_t)n * CHUNKS + chunk] = s;
        }
    }
}

// ---------------- kernel 4: per-row combine of partials ----------------
__global__ __launch_bounds__(256) void row_reduce(
    const float* __restrict__ psum, const float* __restrict__ tgt,
    float* __restrict__ row_loss, int CHUNKS)
{
    const int n = blockIdx.x;
    const int tid = threadIdx.x;
    __shared__ float sm[256];

    float s = 0.f;
    for (int j = tid; j < CHUNKS; j += 256) s += psum[(size_t)n * CHUNKS + j];
    sm[tid] = s; __syncthreads();
    for (int st = 128; st > 0; st >>= 1) {
        if (tid < st) sm[tid] += sm[tid + st];
        __syncthreads();
    }
    if (tid == 0) row_loss[n] = (logf(sm[0]) + AMSM_SCALE) - tgt[n];
}

// ---------------- kernel 5: mean over rows -> scalar ----------------
__global__ __launch_bounds__(256) void final_reduce(
    const float* __restrict__ row_loss, float* __restrict__ out, int N)
{
    const int tid = threadIdx.x;
    __shared__ float sm[256];
    float s = 0.f;
    for (int i = tid; i < N; i += 256) s += row_loss[i];
    sm[tid] = s; __syncthreads();
    for (int st = 128; st > 0; st >>= 1) {
        if (tid < st) sm[tid] += sm[tid + st];
        __syncthreads();
    }
    if (tid == 0) out[0] = sm[0] / (float)N;
}

// ---------------- launch ----------------
extern "C" void kernel_launch(void* const* d_in, const int* in_sizes, int n_in,
                              void* d_out, int out_size, void* d_ws, size_t ws_size,
                              hipStream_t stream) {
    const float* x  = (const float*)d_in[0];
    const float* W  = (const float*)d_in[1];
    const int*   lb = (const int*)d_in[2];
    float* out = (float*)d_out;

    constexpr int N  = 2048, D = 512, C = 100000;
    constexpr int CT = (C + GBN - 1) / GBN;   // 782 column tiles
    constexpr int C_PAD = CT * GBN;           // 100096
    constexpr int CHUNKS = CT * 2;            // 1564 (one per 64-col wave stripe)

    char* ws = (char*)d_ws;
    auto alloc = [&](size_t bytes) {
        char* p = ws; ws += (bytes + 255) & ~(size_t)255; return p;
    };
    __bf16* Wn   = (__bf16*)alloc((size_t)C_PAD * D * sizeof(__bf16)); // 102.5 MB
    __bf16* xn   = (__bf16*)alloc((size_t)N * D * sizeof(__bf16));     // 2 MB
    float*  psum = (float*)alloc((size_t)N * CHUNKS * sizeof(float));  // 12.8 MB
    float*  tgtv = (float*)alloc((size_t)N * sizeof(float));
    float*  rl   = (float*)alloc((size_t)N * sizeof(float));

    rownorm_bf16<<<N / 4, 256, 0, stream>>>(x, xn, N, N);
    rownorm_bf16<<<C_PAD / 4, 256, 0, stream>>>(W, Wn, C, C_PAD);

    dim3 grid(N / GBM, CT);   // m-tiles fastest -> consecutive blocks share W chunk
    amsm_gemm<<<grid, 256, 0, stream>>>(xn, Wn, lb, psum, tgtv, C, CHUNKS);

    row_reduce<<<N, 256, 0, stream>>>(psum, tgtv, rl, CHUNKS);
    final_reduce<<<1, 256, 0, stream>>>(rl, out, N);
}

// Round 5
// 367.876 us; speedup vs baseline: 1.2056x; 1.0761x over previous
//
#include <hip/hip_runtime.h>
#include <hip/hip_bf16.h>
#include <cfloat>
#include <math.h>

// ---------------- types ----------------
typedef __bf16 bf16x8 __attribute__((ext_vector_type(8)));
typedef float  f32x4  __attribute__((ext_vector_type(4)));

#define AMSM_MARGIN 0.35f
#define AMSM_SCALE  30.0f
#define AMSM_EPS    1e-12f

// ---------------- kernel 1/2: row-normalize f32 -> bf16 ----------------
__global__ __launch_bounds__(256) void rownorm_bf16(
    const float* __restrict__ src, __bf16* __restrict__ dst,
    int nrows, int nrows_pad)
{
    int row  = blockIdx.x * 4 + (threadIdx.x >> 6);
    int lane = threadIdx.x & 63;
    if (row >= nrows_pad) return;

    __bf16* drow = dst + (size_t)row * 512 + lane * 8;

    if (row >= nrows) {           // zero-fill pad rows (keeps MFMA garbage-free)
        bf16x8 z = {};
        *(bf16x8*)drow = z;
        return;
    }
    const float4* p = (const float4*)(src + (size_t)row * 512 + lane * 8);
    float4 a = p[0], b = p[1];
    float ss = a.x*a.x + a.y*a.y + a.z*a.z + a.w*a.w
             + b.x*b.x + b.y*b.y + b.z*b.z + b.w*b.w;
    #pragma unroll
    for (int m = 1; m < 64; m <<= 1) ss += __shfl_xor(ss, m, 64);
    float r = 1.0f / sqrtf(ss + AMSM_EPS);

    bf16x8 o;
    o[0] = (__bf16)(a.x*r); o[1] = (__bf16)(a.y*r);
    o[2] = (__bf16)(a.z*r); o[3] = (__bf16)(a.w*r);
    o[4] = (__bf16)(b.x*r); o[5] = (__bf16)(b.y*r);
    o[6] = (__bf16)(b.z*r); o[7] = (__bf16)(b.w*r);
    *(bf16x8*)drow = o;
}

// ---------------- kernel 3: 256x256 8-phase fused GEMM + partial sum-exp ---
// BM=BN=256, BK=64, 8 waves (2M x 4N), per-wave C = 128x64.
// LDS: 8 regions of 16KB: region(b,ab,kh) = b*4 + ab*2 + kh, each [256][32] bf16.
// Phase (ks,nh): 16 MFMA over mi0-7 x {2nh,2nh+1} x k-half ks.
// One half-tile staged per phase; vmcnt(4) at phase 3/7 end; raw s_barrier
// (no vmcnt(0) drain). T2 swizzle: source k-chunk ^((q>>4)&2), read k ^((lo>>2)&2).
#define NTILE  8      // 512 / 64
#define CTILES 391    // 100096 / 256

__device__ __forceinline__ void load_lds16(const void* g, void* l) {
    __builtin_amdgcn_global_load_lds(
        (const __attribute__((address_space(1))) void*)g,
        (__attribute__((address_space(3))) void*)l, 16, 0, 0);
}

#define BAR() __builtin_amdgcn_s_barrier()
#define VMC(N) asm volatile("s_waitcnt vmcnt(" #N ")" ::: "memory")

__global__ __launch_bounds__(512, 2) void amsm_gemm(
    const __bf16* __restrict__ xn, const __bf16* __restrict__ Wn,
    const int* __restrict__ lb,
    float* __restrict__ psum, float* __restrict__ tgt, int C, int CHUNKS)
{
    __shared__ __bf16 lds[8][8192];   // 128 KiB

    // T1: bijective XCD swizzle (3128 = 8 * 391, remainder 0)
    const int bid = blockIdx.x;
    const int wid = (bid & 7) * CTILES + (bid >> 3);
    const int mt  = wid & 7;            // 8 m-tiles, fast -> same-XCD blocks share W band
    const int ct  = wid >> 3;
    const int m0  = mt * 256;
    const int c0  = ct * 256;

    const int tid  = threadIdx.x;
    const int lane = tid & 63;
    const int w    = tid >> 6;
    const int wr   = w >> 2;            // 0..1 (M)
    const int wc   = w & 3;             // 0..3 (N)
    const int g    = lane >> 4;
    const int lo   = lane & 15;

    const __bf16* gA = xn + (size_t)m0 * 512;
    const __bf16* gB = Wn + (size_t)c0 * 512;

    // stage one 16KB half-tile (256 rows x 32 k) into region; pre-swizzled source
    auto stage = [&](int region, const __bf16* gbase) {
        #pragma unroll
        for (int iss = 0; iss < 2; ++iss) {
            const int q   = iss * 512 + tid;
            const int row = q >> 2;
            const int kc  = (q & 3) ^ ((q >> 4) & 2);   // T2 involution (source side)
            load_lds16(gbase + (size_t)row * 512 + kc * 8,
                       (char*)lds + region * 16384 + (iss * 512 + w * 64) * 16);
        }
    };

    const int kxb  = (g ^ ((lo >> 2) & 2)) * 16;        // T2 involution (read side), bytes
    const int aoff = (wr * 128 + lo) * 64 + kxb;        // byte offset within A region
    const int boff = (wc * 64  + lo) * 64 + kxb;        // within B region

    f32x4  acc[8][4] = {};
    bf16x8 af[8], bfr[4];

#define LDA(B, K) { const char* rb_ = (const char*)lds + ((B)*4 + (K))*16384 + aoff; \
    _Pragma("unroll") for (int mi_ = 0; mi_ < 8; ++mi_) \
        af[mi_] = *(const bf16x8*)(rb_ + mi_*1024); }
#define LDB(B, K, N0) { const char* rb_ = (const char*)lds + ((B)*4 + 2 + (K))*16384 + boff; \
    bfr[(N0)]   = *(const bf16x8*)(rb_ + (N0)*1024); \
    bfr[(N0)+1] = *(const bf16x8*)(rb_ + ((N0)+1)*1024); }
#define MM(N0) __builtin_amdgcn_s_setprio(1); \
    _Pragma("unroll") for (int mi_ = 0; mi_ < 8; ++mi_) { \
        acc[mi_][(N0)]   = __builtin_amdgcn_mfma_f32_16x16x32_bf16(af[mi_], bfr[(N0)],   acc[mi_][(N0)],   0,0,0); \
        acc[mi_][(N0)+1] = __builtin_amdgcn_mfma_f32_16x16x32_bf16(af[mi_], bfr[(N0)+1], acc[mi_][(N0)+1], 0,0,0); } \
    __builtin_amdgcn_s_setprio(0);

    // ---- prologue: tile0 complete (buf0), tile1 k0 halves (buf1) ----
    stage(0, gA);            // buf0.A.k0
    stage(2, gB);            // buf0.B.k0
    stage(1, gA + 32);       // buf0.A.k1
    stage(3, gB + 32);       // buf0.B.k1
    stage(4, gA + 64);       // buf1.A.k0
    stage(6, gB + 64);       // buf1.B.k0
    VMC(4);                  // buf0 fully landed; buf1.k0 may fly until ph3's vmcnt
    BAR();

    #pragma unroll
    for (int it = 0; it < 4; ++it) {
        const int t0 = 2 * it;
        const size_t k1 = (size_t)(t0 + 1) * 64;
        const size_t k2 = (size_t)(t0 + 2) * 64;
        const size_t k3 = (size_t)(t0 + 3) * 64;
        const bool s2 = (t0 + 2) < NTILE;   // constant after unroll
        const bool s3 = (t0 + 3) < NTILE;

        // ph0: read buf0.ks0 (A + B ni0,1); stage buf1.A.k1 <- tile t0+1
        LDA(0,0); LDB(0,0,0);
        stage(5, gA + k1 + 32);
        BAR(); MM(0); BAR();
        // ph1: read buf0.ks0 (B ni2,3); stage buf1.B.k1 <- t0+1
        LDB(0,0,2);
        stage(7, gB + k1 + 32);
        BAR(); MM(2); BAR();
        // ph2: read buf0.ks1 (A + B ni0,1); stage buf0.A.k0 <- t0+2
        LDA(0,1); LDB(0,1,0);
        if (s2) stage(0, gA + k2);
        BAR(); MM(0); BAR();
        // ph3: read buf0.ks1 (B ni2,3); stage buf0.B.k0 <- t0+2; vmcnt
        LDB(0,1,2);
        if (s2) stage(2, gB + k2);
        BAR(); MM(2);
        if (s2) { VMC(4); } else { VMC(0); }   // buf1 (t0+1) fully landed
        BAR();
        // ph4: read buf1.ks0 (A + B ni0,1); stage buf0.A.k1 <- t0+2
        LDA(1,0); LDB(1,0,0);
        if (s2) stage(1, gA + k2 + 32);
        BAR(); MM(0); BAR();
        // ph5: read buf1.ks0 (B ni2,3); stage buf0.B.k1 <- t0+2
        LDB(1,0,2);
        if (s2) stage(3, gB + k2 + 32);
        BAR(); MM(2); BAR();
        // ph6: read buf1.ks1 (A + B ni0,1); stage buf1.A.k0 <- t0+3
        LDA(1,1); LDB(1,1,0);
        if (s3) stage(4, gA + k3);
        BAR(); MM(0); BAR();
        // ph7: read buf1.ks1 (B ni2,3); stage buf1.B.k0 <- t0+3; vmcnt
        LDB(1,1,2);
        if (s3) stage(6, gB + k3);
        BAR(); MM(2);
        if (s3) { VMC(4); } else { VMC(0); }   // buf0 (t0+2) fully landed
        BAR();
    }

    // ---- epilogue: C/D map col=lane&15 (class), row=(lane>>4)*4+reg (x-row) ----
    const int n_base = m0 + wr * 128;
    const int c_base = c0 + wc * 64;
    const int chunk  = ct * 4 + wc;

    #pragma unroll
    for (int mi = 0; mi < 8; ++mi) {
        #pragma unroll
        for (int j = 0; j < 4; ++j) {
            const int n = n_base + mi * 16 + g * 4 + j;
            const int target = lb[n];
            float s = 0.f;
            #pragma unroll
            for (int ni = 0; ni < 4; ++ni) {
                const int c = c_base + ni * 16 + lo;
                float logit = AMSM_SCALE * acc[mi][ni][j];
                if (c == target) {
                    logit -= AMSM_SCALE * AMSM_MARGIN;
                    tgt[n] = logit;                    // unique writer globally
                }
                // analytic bound: logit <= SCALE; exp(logit-SCALE) in [2.6e-31, 1]
                s += (c < C) ? __expf(logit - AMSM_SCALE) : 0.f;
            }
            #pragma unroll
            for (int m_ = 1; m_ < 16; m_ <<= 1) s += __shfl_xor(s, m_, 64);
            if (lo == 0) psum[(size_t)n * CHUNKS + chunk] = s;
        }
    }
#undef LDA
#undef LDB
#undef MM
}

// ---------------- kernel 4: per-row combine of partials ----------------
__global__ __launch_bounds__(256) void row_reduce(
    const float* __restrict__ psum, const float* __restrict__ tgt,
    float* __restrict__ row_loss, int CHUNKS)
{
    const int n = blockIdx.x;
    const int tid = threadIdx.x;
    __shared__ float sm[256];

    float s = 0.f;
    for (int j = tid; j < CHUNKS; j += 256) s += psum[(size_t)n * CHUNKS + j];
    sm[tid] = s; __syncthreads();
    for (int st = 128; st > 0; st >>= 1) {
        if (tid < st) sm[tid] += sm[tid + st];
        __syncthreads();
    }
    if (tid == 0) row_loss[n] = (logf(sm[0]) + AMSM_SCALE) - tgt[n];
}

// ---------------- kernel 5: mean over rows -> scalar ----------------
__global__ __launch_bounds__(256) void final_reduce(
    const float* __restrict__ row_loss, float* __restrict__ out, int N)
{
    const int tid = threadIdx.x;
    __shared__ float sm[256];
    float s = 0.f;
    for (int i = tid; i < N; i += 256) s += row_loss[i];
    sm[tid] = s; __syncthreads();
    for (int st = 128; st > 0; st >>= 1) {
        if (tid < st) sm[tid] += sm[tid + st];
        __syncthreads();
    }
    if (tid == 0) out[0] = sm[0] / (float)N;
}

// ---------------- launch ----------------
extern "C" void kernel_launch(void* const* d_in, const int* in_sizes, int n_in,
                              void* d_out, int out_size, void* d_ws, size_t ws_size,
                              hipStream_t stream) {
    const float* x  = (const float*)d_in[0];
    const float* W  = (const float*)d_in[1];
    const int*   lb = (const int*)d_in[2];
    float* out = (float*)d_out;

    constexpr int N  = 2048, D = 512, C = 100000;
    constexpr int C_PAD  = CTILES * 256;     // 100096
    constexpr int CHUNKS = CTILES * 4;       // 1564 (one per 64-col wave stripe)

    char* ws = (char*)d_ws;
    auto alloc = [&](size_t bytes) {
        char* p = ws; ws += (bytes + 255) & ~(size_t)255; return p;
    };
    __bf16* Wn   = (__bf16*)alloc((size_t)C_PAD * D * sizeof(__bf16)); // 102.5 MB
    __bf16* xn   = (__bf16*)alloc((size_t)N * D * sizeof(__bf16));     // 2 MB
    float*  psum = (float*)alloc((size_t)N * CHUNKS * sizeof(float));  // 12.8 MB
    float*  tgtv = (float*)alloc((size_t)N * sizeof(float));
    float*  rl   = (float*)alloc((size_t)N * sizeof(float));

    rownorm_bf16<<<N / 4, 256, 0, stream>>>(x, xn, N, N);
    rownorm_bf16<<<C_PAD / 4, 256, 0, stream>>>(W, Wn, C, C_PAD);

    amsm_gemm<<<8 * CTILES, 512, 0, stream>>>(xn, Wn, lb, psum, tgtv, C, CHUNKS);

    row_reduce<<<N, 256, 0, stream>>>(psum, tgtv, rl, CHUNKS);
    final_reduce<<<1, 256, 0, stream>>>(rl, out, N);
}